// Round 1
// baseline (312.348 us; speedup 1.0000x reference)
//
#include <hip/hip_runtime.h>
#include <hip/hip_bf16.h>
#include <math.h>

// Problem constants
#define BB 8
#define LL 128
#define DD 512
#define EE 64
#define HH 8
#define CC 64        // D/H
#define SLOPE 0.2f
#define EPS 1e-5f
#define LPAD 65      // e-tile LDS row stride (bank-conflict padding)

// ---------------------------------------------------------------------------
// Kernel 1: Q = x @ Wq, KV = x @ Wkv, stored in (B,H,L,C) layout.
// One block per (b,l) row; 256 threads; each thread computes 2 output cols.
// ---------------------------------------------------------------------------
__global__ __launch_bounds__(256) void proj_kernel(
    const float* __restrict__ x, const float* __restrict__ Wq,
    const float* __restrict__ Wkv, float* __restrict__ Q, float* __restrict__ KV)
{
    const int row = blockIdx.x;          // b*L + l
    const int b = row >> 7, l = row & 127;
    __shared__ float xr[DD];
    for (int i = threadIdx.x; i < DD; i += 256) xr[i] = x[row * DD + i];
    __syncthreads();
    for (int d = threadIdx.x; d < DD; d += 256) {
        float aq = 0.f, ak = 0.f;
        #pragma unroll 4
        for (int k = 0; k < DD; ++k) {
            const float xv = xr[k];
            aq += xv * Wq[k * DD + d];
            ak += xv * Wkv[k * DD + d];
        }
        const int h = d >> 6, c = d & 63;
        const int idx = (((b * HH + h) * LL) + l) * CC + c;
        Q[idx] = aq;
        KV[idx] = ak;
    }
}

// ---------------------------------------------------------------------------
// Kernel 2: fused edge attention for one (b,q) pair per block.
//   T[h,x]   = sum_c We[x, h*C+c] * q[b,h,q,c]
//   s[h,k]   = leaky( (q.kv_k + e_row_k . T_h) / sqrt(C) ), masked by adj
//   softmax over k (normalization folded into epilogue)
//   g[h,x]   = sum_k s[h,k] * e[b,q,k,x]
//   out[h,c] = ( sum_k s[h,k]*KV[b,h,k,c] + sum_x g[h,x]*We[x,h*C+c] ) * invl[h]
// ---------------------------------------------------------------------------
__global__ __launch_bounds__(256) void attn_kernel(
    const float* __restrict__ Q, const float* __restrict__ KV,
    const float* __restrict__ e, const int* __restrict__ adj,
    const float* __restrict__ We, float* __restrict__ attn_out)
{
    __shared__ float et[LL * LPAD];      // e tile, padded
    __shared__ float qrow[DD];
    __shared__ float T[HH * EE];
    __shared__ float s[HH * LL];
    __shared__ float g[HH * EE];
    __shared__ float mh[HH];
    __shared__ float invl[HH];

    const int row = blockIdx.x;          // b*L + q
    const int b = row >> 7, q = row & 127;
    const int tid = threadIdx.x;

    // stage e[b,q,:,:] into LDS (coalesced global, padded LDS rows)
    const float* ebase = e + (size_t)row * (LL * EE);
    for (int i = tid; i < LL * EE; i += 256) {
        const int k = i >> 6, xx = i & 63;
        et[k * LPAD + xx] = ebase[i];
    }
    // stage q row (all heads)
    for (int i = tid; i < DD; i += 256) {
        const int h = i >> 6, c = i & 63;
        qrow[i] = Q[(((b * HH + h) * LL) + q) * CC + c];
    }
    __syncthreads();

    // T[h,x]
    for (int i = tid; i < HH * EE; i += 256) {
        const int h = i >> 6, xx = i & 63;
        float acc = 0.f;
        #pragma unroll 8
        for (int c = 0; c < CC; ++c)
            acc += We[xx * DD + h * CC + c] * qrow[h * CC + c];
        T[i] = acc;
    }
    __syncthreads();

    // raw scores with leaky-relu + adjacency mask
    for (int p = tid; p < HH * LL; p += 256) {
        const int h = p >> 7, k = p & 127;
        float a1 = 0.f;
        const float* kvp = KV + (((b * HH + h) * LL) + k) * CC;
        #pragma unroll 8
        for (int c = 0; c < CC; ++c) a1 += qrow[h * CC + c] * kvp[c];
        float a2 = 0.f;
        #pragma unroll 8
        for (int xx = 0; xx < EE; ++xx) a2 += et[k * LPAD + xx] * T[h * EE + xx];
        float sc = (a1 + a2) * 0.125f;               // 1/sqrt(64)
        sc = (sc >= 0.f) ? sc : SLOPE * sc;          // leaky relu
        if (adj[(b * LL + q) * LL + k] == 0) sc = -1e9f;
        s[p] = sc;
    }
    __syncthreads();

    // per-head max
    if (tid < HH) {
        float m = -INFINITY;
        for (int k = 0; k < LL; ++k) m = fmaxf(m, s[tid * LL + k]);
        mh[tid] = m;
    }
    __syncthreads();

    // exponentiate in place (unnormalized)
    for (int p = tid; p < HH * LL; p += 256) {
        const int h = p >> 7;
        s[p] = expf(s[p] - mh[h]);
    }
    __syncthreads();

    // per-head sum -> inverse
    if (tid < HH) {
        float l = 0.f;
        for (int k = 0; k < LL; ++k) l += s[tid * LL + k];
        invl[tid] = 1.f / l;
    }
    __syncthreads();

    // g[h,x] = sum_k s[h,k] * et[k,x]
    for (int i = tid; i < HH * EE; i += 256) {
        const int h = i >> 6, xx = i & 63;
        float acc = 0.f;
        #pragma unroll 4
        for (int k = 0; k < LL; ++k) acc += s[h * LL + k] * et[k * LPAD + xx];
        g[i] = acc;
    }
    __syncthreads();

    // out[h,c]
    for (int i = tid; i < DD; i += 256) {
        const int h = i >> 6, c = i & 63;
        float acc = 0.f;
        const float* kvp = KV + ((b * HH + h) * LL) * CC + c;
        #pragma unroll 4
        for (int k = 0; k < LL; ++k) acc += s[h * LL + k] * kvp[k * CC];
        float acc2 = 0.f;
        #pragma unroll 8
        for (int xx = 0; xx < EE; ++xx) acc2 += g[h * EE + xx] * We[xx * DD + h * CC + c];
        attn_out[row * DD + i] = (acc + acc2) * invl[h];
    }
}

// ---------------------------------------------------------------------------
// Kernel 3: FFN (attn @ Wf + bf) -> LayerNorm -> ReLU.  One block per row.
// ---------------------------------------------------------------------------
__global__ __launch_bounds__(256) void ffn_kernel(
    const float* __restrict__ attn, const float* __restrict__ Wf,
    const float* __restrict__ bfv, const float* __restrict__ gamma,
    const float* __restrict__ beta, float* __restrict__ out)
{
    __shared__ float rowv[DD];
    __shared__ float vals[DD];
    __shared__ float red[8];
    __shared__ float stats[2];
    const int row = blockIdx.x;
    const int tid = threadIdx.x;

    for (int i = tid; i < DD; i += 256) rowv[i] = attn[row * DD + i];
    __syncthreads();

    float acc0 = bfv[tid], acc1 = bfv[tid + 256];
    #pragma unroll 4
    for (int k = 0; k < DD; ++k) {
        const float rv = rowv[k];
        acc0 += rv * Wf[k * DD + tid];
        acc1 += rv * Wf[k * DD + tid + 256];
    }
    vals[tid] = acc0;
    vals[tid + 256] = acc1;

    // reduce sum and sumsq: wave (64) shuffle then cross-wave via LDS
    float ls = acc0 + acc1;
    float lss = acc0 * acc0 + acc1 * acc1;
    #pragma unroll
    for (int off = 32; off > 0; off >>= 1) {
        ls += __shfl_down(ls, off);
        lss += __shfl_down(lss, off);
    }
    const int wid = tid >> 6;
    if ((tid & 63) == 0) { red[wid * 2] = ls; red[wid * 2 + 1] = lss; }
    __syncthreads();
    if (tid == 0) {
        float ts = 0.f, tss = 0.f;
        for (int w = 0; w < 4; ++w) { ts += red[w * 2]; tss += red[w * 2 + 1]; }
        const float mu = ts / (float)DD;
        const float var = tss / (float)DD - mu * mu;
        stats[0] = mu;
        stats[1] = rsqrtf(var + EPS);
    }
    __syncthreads();
    const float mu = stats[0], rsig = stats[1];
    {
        float v0 = (vals[tid] - mu) * rsig * gamma[tid] + beta[tid];
        float v1 = (vals[tid + 256] - mu) * rsig * gamma[tid + 256] + beta[tid + 256];
        out[row * DD + tid] = fmaxf(v0, 0.f);
        out[row * DD + tid + 256] = fmaxf(v1, 0.f);
    }
}

// ---------------------------------------------------------------------------
extern "C" void kernel_launch(void* const* d_in, const int* in_sizes, int n_in,
                              void* d_out, int out_size, void* d_ws, size_t ws_size,
                              hipStream_t stream)
{
    const float* x    = (const float*)d_in[0];
    const int*   adj  = (const int*)  d_in[1];
    const float* e    = (const float*)d_in[2];
    const float* Wq   = (const float*)d_in[3];
    const float* Wkv  = (const float*)d_in[4];
    const float* We   = (const float*)d_in[5];
    const float* Wf   = (const float*)d_in[6];
    const float* bf   = (const float*)d_in[7];
    const float* gam  = (const float*)d_in[8];
    const float* bet  = (const float*)d_in[9];
    float* out = (float*)d_out;

    float* Q    = (float*)d_ws;                      // B*H*L*C = 524288 floats
    float* KV   = Q + BB * HH * LL * CC;             // 524288 floats
    float* attn = KV + BB * HH * LL * CC;            // B*L*D   = 524288 floats

    proj_kernel<<<BB * LL, 256, 0, stream>>>(x, Wq, Wkv, Q, KV);
    attn_kernel<<<BB * LL, 256, 0, stream>>>(Q, KV, e, adj, We, attn);
    ffn_kernel<<<BB * LL, 256, 0, stream>>>(attn, Wf, bf, gam, bet, out);
}

// Round 2
// 213.507 us; speedup vs baseline: 1.4629x; 1.4629x over previous
//
#include <hip/hip_runtime.h>
#include <hip/hip_bf16.h>
#include <math.h>

// Problem constants
#define BB 8
#define LL 128
#define DD 512
#define EE 64
#define HH 8
#define CC 64        // D/H
#define SLOPE 0.2f
#define EPS 1e-5f
#define LPAD 65      // e-tile LDS row stride (bank-conflict padding)

typedef short bf16x8v __attribute__((ext_vector_type(8)));
typedef float f32x4v __attribute__((ext_vector_type(4)));

static __device__ __forceinline__ unsigned short f2bf(float f) {
    union { float f; unsigned u; } v; v.f = f;
    unsigned r = v.u + 0x7FFFu + ((v.u >> 16) & 1u);   // RNE
    return (unsigned short)(r >> 16);
}

// ---------------------------------------------------------------------------
// Pack kernels: fp32 -> bf16 (bits in ushort)
// ---------------------------------------------------------------------------
__global__ __launch_bounds__(256) void cast_x_kernel(
    const float* __restrict__ in, unsigned short* __restrict__ out, int n4)
{
    int i = blockIdx.x * 256 + threadIdx.x;
    if (i < n4) {
        const float4 v = ((const float4*)in)[i];
        ushort4 o;
        o.x = f2bf(v.x); o.y = f2bf(v.y); o.z = f2bf(v.z); o.w = f2bf(v.w);
        ((ushort4*)out)[i] = o;
    }
}

// in: K x N fp32 (row-major), out: N x K bf16 (row-major) — i.e. out = in^T
__global__ __launch_bounds__(256) void transpose_cast_kernel(
    const float* __restrict__ in, unsigned short* __restrict__ out, int K, int N)
{
    __shared__ float tile[32][33];
    const int x = threadIdx.x & 31;
    const int y = threadIdx.x >> 5;          // 0..7
    const int c0 = blockIdx.x * 32;          // col tile in `in`
    const int r0 = blockIdx.y * 32;          // row tile in `in`
    #pragma unroll
    for (int j = 0; j < 32; j += 8)
        tile[y + j][x] = in[(r0 + y + j) * N + c0 + x];
    __syncthreads();
    #pragma unroll
    for (int j = 0; j < 32; j += 8)
        out[(c0 + y + j) * K + r0 + x] = f2bf(tile[x][y + j]);
}

// ---------------------------------------------------------------------------
// MFMA GEMM (16x16x32 bf16). A: MxK row-major bf16. Bm: NxK row-major (B^T).
// Block = 4 waves, tile 64(m) x 64(n); wave w covers rows m0+w*16..+15,
// 4 b-frags across n. Fragment layouts (HW-verified, see guide §3):
//   A[m=lane&15][k=quad*8+j]  B[k=quad*8+j][n=lane&15]  D[quad*4+r][lane&15]
// ---------------------------------------------------------------------------
__global__ __launch_bounds__(256) void gemm_proj_kernel(
    const unsigned short* __restrict__ A, const unsigned short* __restrict__ Bm,
    float* __restrict__ Q, float* __restrict__ KV)
{
    const int wave = threadIdx.x >> 6, lane = threadIdx.x & 63;
    const int quad = lane >> 4, l16 = lane & 15;
    const int m0 = blockIdx.y * 64 + wave * 16;
    const int n0 = blockIdx.x * 64;
    const bf16x8v* Ap  = (const bf16x8v*)(A + (m0 + l16) * DD) + quad;
    const bf16x8v* Bp  = (const bf16x8v*)(Bm + (n0 + l16) * DD) + quad;
    f32x4v acc0 = {0.f,0.f,0.f,0.f}, acc1 = acc0, acc2 = acc0, acc3 = acc0;
    #pragma unroll 4
    for (int k = 0; k < 16; ++k) {          // K = 512 = 16 * 32
        const bf16x8v a = Ap[k * 4];
        acc0 = __builtin_amdgcn_mfma_f32_16x16x32_bf16(a, Bp[k * 4         ], acc0, 0, 0, 0);
        acc1 = __builtin_amdgcn_mfma_f32_16x16x32_bf16(a, Bp[k * 4 + 1024  ], acc1, 0, 0, 0);
        acc2 = __builtin_amdgcn_mfma_f32_16x16x32_bf16(a, Bp[k * 4 + 2048  ], acc2, 0, 0, 0);
        acc3 = __builtin_amdgcn_mfma_f32_16x16x32_bf16(a, Bp[k * 4 + 3072  ], acc3, 0, 0, 0);
    }
    const f32x4v accs[4] = {acc0, acc1, acc2, acc3};
    #pragma unroll
    for (int t = 0; t < 4; ++t) {
        const int gn = n0 + t * 16 + l16;
        const int mat = gn >> 9, d = gn & 511, h = d >> 6, c = d & 63;
        float* dst = mat ? KV : Q;
        #pragma unroll
        for (int r = 0; r < 4; ++r) {
            const int gm = m0 + quad * 4 + r;
            const int b = gm >> 7, l = gm & 127;
            dst[((b * HH + h) * LL + l) * CC + c] = accs[t][r];
        }
    }
}

// A: attn_bf (1024x512), Bm: Wf^T (512x512). vals = A@Wf + bf (fp32)
__global__ __launch_bounds__(256) void gemm_ffn_kernel(
    const unsigned short* __restrict__ A, const unsigned short* __restrict__ Bm,
    const float* __restrict__ bfv, float* __restrict__ vals)
{
    const int wave = threadIdx.x >> 6, lane = threadIdx.x & 63;
    const int quad = lane >> 4, l16 = lane & 15;
    const int m0 = blockIdx.y * 64 + wave * 16;
    const int n0 = blockIdx.x * 64;
    const bf16x8v* Ap  = (const bf16x8v*)(A + (m0 + l16) * DD) + quad;
    const bf16x8v* Bp  = (const bf16x8v*)(Bm + (n0 + l16) * DD) + quad;
    f32x4v acc0 = {0.f,0.f,0.f,0.f}, acc1 = acc0, acc2 = acc0, acc3 = acc0;
    #pragma unroll 4
    for (int k = 0; k < 16; ++k) {
        const bf16x8v a = Ap[k * 4];
        acc0 = __builtin_amdgcn_mfma_f32_16x16x32_bf16(a, Bp[k * 4         ], acc0, 0, 0, 0);
        acc1 = __builtin_amdgcn_mfma_f32_16x16x32_bf16(a, Bp[k * 4 + 1024  ], acc1, 0, 0, 0);
        acc2 = __builtin_amdgcn_mfma_f32_16x16x32_bf16(a, Bp[k * 4 + 2048  ], acc2, 0, 0, 0);
        acc3 = __builtin_amdgcn_mfma_f32_16x16x32_bf16(a, Bp[k * 4 + 3072  ], acc3, 0, 0, 0);
    }
    const f32x4v accs[4] = {acc0, acc1, acc2, acc3};
    #pragma unroll
    for (int t = 0; t < 4; ++t) {
        const int gn = n0 + t * 16 + l16;
        const float bias = bfv[gn];
        #pragma unroll
        for (int r = 0; r < 4; ++r) {
            const int gm = m0 + quad * 4 + r;
            vals[gm * DD + gn] = accs[t][r] + bias;
        }
    }
}

// ---------------------------------------------------------------------------
// Kernel 2: fused edge attention, one (b,q) per block (unchanged math,
// parallel softmax reductions, bf16 output for the FFN MFMA GEMM).
// ---------------------------------------------------------------------------
__global__ __launch_bounds__(256) void attn_kernel(
    const float* __restrict__ Q, const float* __restrict__ KV,
    const float* __restrict__ e, const int* __restrict__ adj,
    const float* __restrict__ We, unsigned short* __restrict__ attn_bf)
{
    __shared__ float et[LL * LPAD];
    __shared__ float qrow[DD];
    __shared__ float T[HH * EE];
    __shared__ float s[HH * LL];
    __shared__ float g[HH * EE];
    __shared__ float mh[HH];
    __shared__ float invl[HH];

    const int row = blockIdx.x;          // b*L + q
    const int b = row >> 7, q = row & 127;
    const int tid = threadIdx.x;

    const float* ebase = e + (size_t)row * (LL * EE);
    for (int i = tid; i < LL * EE; i += 256) {
        const int k = i >> 6, xx = i & 63;
        et[k * LPAD + xx] = ebase[i];
    }
    for (int i = tid; i < DD; i += 256) {
        const int h = i >> 6, c = i & 63;
        qrow[i] = Q[(((b * HH + h) * LL) + q) * CC + c];
    }
    __syncthreads();

    // T[h,x] = sum_c We[x, h*C+c] * q[h,c]
    for (int i = tid; i < HH * EE; i += 256) {
        const int h = i >> 6, xx = i & 63;
        float acc = 0.f;
        #pragma unroll 8
        for (int c = 0; c < CC; ++c)
            acc += We[xx * DD + h * CC + c] * qrow[h * CC + c];
        T[i] = acc;
    }
    __syncthreads();

    // raw scores
    for (int p = tid; p < HH * LL; p += 256) {
        const int h = p >> 7, k = p & 127;
        float a1 = 0.f;
        const float* kvp = KV + (((b * HH + h) * LL) + k) * CC;
        #pragma unroll 8
        for (int c = 0; c < CC; ++c) a1 += qrow[h * CC + c] * kvp[c];
        float a2 = 0.f;
        #pragma unroll 8
        for (int xx = 0; xx < EE; ++xx) a2 += et[k * LPAD + xx] * T[h * EE + xx];
        float sc = (a1 + a2) * 0.125f;
        sc = (sc >= 0.f) ? sc : SLOPE * sc;
        if (adj[(b * LL + q) * LL + k] == 0) sc = -1e9f;
        s[p] = sc;
    }
    __syncthreads();

    // per-head max: 32 threads per head + width-32 shuffle reduce
    {
        const int h = tid >> 5, t5 = tid & 31;
        float m = -INFINITY;
        for (int k = t5; k < LL; k += 32) m = fmaxf(m, s[h * LL + k]);
        #pragma unroll
        for (int off = 16; off > 0; off >>= 1) m = fmaxf(m, __shfl_down(m, off, 32));
        if (t5 == 0) mh[h] = m;
    }
    __syncthreads();

    for (int p = tid; p < HH * LL; p += 256) {
        const int h = p >> 7;
        s[p] = expf(s[p] - mh[h]);
    }
    __syncthreads();

    {
        const int h = tid >> 5, t5 = tid & 31;
        float l = 0.f;
        for (int k = t5; k < LL; k += 32) l += s[h * LL + k];
        #pragma unroll
        for (int off = 16; off > 0; off >>= 1) l += __shfl_down(l, off, 32);
        if (t5 == 0) invl[h] = 1.f / l;
    }
    __syncthreads();

    // g[h,x] = sum_k s[h,k] * et[k,x]
    for (int i = tid; i < HH * EE; i += 256) {
        const int h = i >> 6, xx = i & 63;
        float acc = 0.f;
        #pragma unroll 4
        for (int k = 0; k < LL; ++k) acc += s[h * LL + k] * et[k * LPAD + xx];
        g[i] = acc;
    }
    __syncthreads();

    // out[h,c] -> bf16 row
    for (int i = tid; i < DD; i += 256) {
        const int h = i >> 6, c = i & 63;
        float acc = 0.f;
        const float* kvp = KV + ((b * HH + h) * LL) * CC + c;
        #pragma unroll 4
        for (int k = 0; k < LL; ++k) acc += s[h * LL + k] * kvp[k * CC];
        float acc2 = 0.f;
        #pragma unroll 8
        for (int xx = 0; xx < EE; ++xx) acc2 += g[h * EE + xx] * We[xx * DD + h * CC + c];
        attn_bf[row * DD + i] = f2bf((acc + acc2) * invl[h]);
    }
}

// ---------------------------------------------------------------------------
// LayerNorm + ReLU over vals rows
// ---------------------------------------------------------------------------
__global__ __launch_bounds__(256) void ln_kernel(
    const float* __restrict__ vals, const float* __restrict__ gamma,
    const float* __restrict__ beta, float* __restrict__ out)
{
    __shared__ float red[8];
    __shared__ float stats[2];
    const int row = blockIdx.x;
    const int tid = threadIdx.x;

    const float v0 = vals[row * DD + tid];
    const float v1 = vals[row * DD + tid + 256];

    float ls = v0 + v1;
    float lss = v0 * v0 + v1 * v1;
    #pragma unroll
    for (int off = 32; off > 0; off >>= 1) {
        ls += __shfl_down(ls, off);
        lss += __shfl_down(lss, off);
    }
    const int wid = tid >> 6;
    if ((tid & 63) == 0) { red[wid * 2] = ls; red[wid * 2 + 1] = lss; }
    __syncthreads();
    if (tid == 0) {
        float ts = 0.f, tss = 0.f;
        for (int w = 0; w < 4; ++w) { ts += red[w * 2]; tss += red[w * 2 + 1]; }
        const float mu = ts / (float)DD;
        const float var = tss / (float)DD - mu * mu;
        stats[0] = mu;
        stats[1] = rsqrtf(var + EPS);
    }
    __syncthreads();
    const float mu = stats[0], rsig = stats[1];
    const float o0 = (v0 - mu) * rsig * gamma[tid] + beta[tid];
    const float o1 = (v1 - mu) * rsig * gamma[tid + 256] + beta[tid + 256];
    out[row * DD + tid] = fmaxf(o0, 0.f);
    out[row * DD + tid + 256] = fmaxf(o1, 0.f);
}

// ---------------------------------------------------------------------------
extern "C" void kernel_launch(void* const* d_in, const int* in_sizes, int n_in,
                              void* d_out, int out_size, void* d_ws, size_t ws_size,
                              hipStream_t stream)
{
    const float* x    = (const float*)d_in[0];
    const int*   adj  = (const int*)  d_in[1];
    const float* e    = (const float*)d_in[2];
    const float* Wq   = (const float*)d_in[3];
    const float* Wkv  = (const float*)d_in[4];
    const float* We   = (const float*)d_in[5];
    const float* Wf   = (const float*)d_in[6];
    const float* bf   = (const float*)d_in[7];
    const float* gam  = (const float*)d_in[8];
    const float* bet  = (const float*)d_in[9];
    float* out = (float*)d_out;

    const int MROW = BB * LL;            // 1024
    float* Q    = (float*)d_ws;                       // 524288 f
    float* KV   = Q + MROW * DD;                      // 524288 f
    float* vals = KV + MROW * DD;                     // 524288 f
    unsigned short* xb      = (unsigned short*)(vals + MROW * DD);  // 524288
    unsigned short* Wqkv_t  = xb + MROW * DD;                       // 524288 (=[Wq^T;Wkv^T])
    unsigned short* Wf_t    = Wqkv_t + 2 * DD * DD;                 // 262144
    unsigned short* attn_bf = Wf_t + DD * DD;                       // 524288

    // pack
    cast_x_kernel<<<(MROW * DD / 4 + 255) / 256, 256, 0, stream>>>(x, xb, MROW * DD / 4);
    transpose_cast_kernel<<<dim3(16, 16), 256, 0, stream>>>(Wq,  Wqkv_t,           DD, DD);
    transpose_cast_kernel<<<dim3(16, 16), 256, 0, stream>>>(Wkv, Wqkv_t + DD * DD, DD, DD);
    transpose_cast_kernel<<<dim3(16, 16), 256, 0, stream>>>(Wf,  Wf_t,             DD, DD);

    // projections (M=1024, N=1024, K=512)
    gemm_proj_kernel<<<dim3(16, 16), 256, 0, stream>>>(xb, Wqkv_t, Q, KV);
    // attention
    attn_kernel<<<MROW, 256, 0, stream>>>(Q, KV, e, adj, We, attn_bf);
    // FFN GEMM (M=1024, N=512, K=512) + bias
    gemm_ffn_kernel<<<dim3(8, 16), 256, 0, stream>>>(attn_bf, Wf_t, bf, vals);
    // LayerNorm + ReLU
    ln_kernel<<<MROW, 256, 0, stream>>>(vals, gam, bet, out);
}

// Round 3
// 140.087 us; speedup vs baseline: 2.2297x; 1.5241x over previous
//
#include <hip/hip_runtime.h>
#include <hip/hip_bf16.h>
#include <math.h>

// Problem constants
#define BB 8
#define LL 128
#define DD 512
#define EE 64
#define HH 8
#define CC 64        // D/H
#define SLOPE 0.2f
#define EPS 1e-5f

typedef short bf16x8v __attribute__((ext_vector_type(8)));
typedef float f32x4v __attribute__((ext_vector_type(4)));

static __device__ __forceinline__ unsigned short f2bf(float f) {
    union { float f; unsigned u; } v; v.f = f;
    unsigned r = v.u + 0x7FFFu + ((v.u >> 16) & 1u);   // RNE
    return (unsigned short)(r >> 16);
}

// ---------------------------------------------------------------------------
// pack_all: x->bf16; Wq/Wkv/Wf transpose-cast; We cast; We transpose-cast.
// Grid sections by blockIdx.x:
//   [0,256)     x cast (1024x512)
//   [256,1024)  W transposes (3 x 512x512, 256 tiles each)
//   [1024,1040) We cast (64x512)
//   [1040,1072) WeT transpose (We 64x512 -> WeT 512x64)
// ---------------------------------------------------------------------------
__global__ __launch_bounds__(256) void pack_all(
    const float* __restrict__ x, const float* __restrict__ Wq,
    const float* __restrict__ Wkv, const float* __restrict__ Wf,
    const float* __restrict__ We,
    unsigned short* __restrict__ xb, unsigned short* __restrict__ Wqkv_t,
    unsigned short* __restrict__ Wf_t, unsigned short* __restrict__ We_bf,
    unsigned short* __restrict__ WeT_bf)
{
    const int blk = blockIdx.x, tid = threadIdx.x;
    if (blk < 256) {                       // x cast: 512 float4 per block
        const int j = blk * 512 + tid * 2;
        #pragma unroll
        for (int i = 0; i < 2; ++i) {
            const float4 v = ((const float4*)x)[j + i];
            ushort4 u; u.x = f2bf(v.x); u.y = f2bf(v.y); u.z = f2bf(v.z); u.w = f2bf(v.w);
            ((ushort4*)xb)[j + i] = u;
        }
    } else if (blk < 1024) {               // 512x512 transpose-cast
        __shared__ float tile[32][33];
        const int matId = (blk - 256) >> 8;
        const int t = (blk - 256) & 255;
        const float* src = matId == 0 ? Wq : (matId == 1 ? Wkv : Wf);
        unsigned short* dst = matId == 0 ? Wqkv_t : (matId == 1 ? Wqkv_t + DD * DD : Wf_t);
        const int xx = tid & 31, yy = tid >> 5;
        const int r0 = (t >> 4) * 32, c0 = (t & 15) * 32;
        #pragma unroll
        for (int j = 0; j < 32; j += 8)
            tile[yy + j][xx] = src[(r0 + yy + j) * DD + c0 + xx];
        __syncthreads();
        #pragma unroll
        for (int j = 0; j < 32; j += 8)
            dst[(c0 + yy + j) * DD + r0 + xx] = f2bf(tile[xx][yy + j]);
    } else if (blk < 1040) {               // We cast: 64x512 = 8192 float4
        const int j = (blk - 1024) * 512 + tid * 2;
        #pragma unroll
        for (int i = 0; i < 2; ++i) {
            const float4 v = ((const float4*)We)[j + i];
            ushort4 u; u.x = f2bf(v.x); u.y = f2bf(v.y); u.z = f2bf(v.z); u.w = f2bf(v.w);
            ((ushort4*)We_bf)[j + i] = u;
        }
    } else {                               // WeT: We(64x512) -> (512x64)
        __shared__ float tile[32][33];
        const int t = blk - 1040;
        const int xx = tid & 31, yy = tid >> 5;
        const int r0 = (t >> 4) * 32, c0 = (t & 15) * 32;   // r0 in [0,64), c0 in [0,512)
        #pragma unroll
        for (int j = 0; j < 32; j += 8)
            tile[yy + j][xx] = We[(r0 + yy + j) * DD + c0 + xx];
        __syncthreads();
        #pragma unroll
        for (int j = 0; j < 32; j += 8)
            WeT_bf[(c0 + yy + j) * EE + r0 + xx] = f2bf(tile[xx][yy + j]);
    }
}

// ---------------------------------------------------------------------------
// proj_gemm: [Q|KV](1024x1024) = xb(1024x512) @ [Wq|Wkv]; epilogue writes
// Q_bf, KV_bf as (bq,d) bf16 and KVT_bf as (b,h,c,k=l) bf16.
// ---------------------------------------------------------------------------
__global__ __launch_bounds__(256) void proj_gemm(
    const unsigned short* __restrict__ A, const unsigned short* __restrict__ Bm,
    unsigned short* __restrict__ Q_bf, unsigned short* __restrict__ KV_bf,
    unsigned short* __restrict__ KVT_bf)
{
    const int wave = threadIdx.x >> 6, lane = threadIdx.x & 63;
    const int quad = lane >> 4, l16 = lane & 15;
    const int m0 = blockIdx.y * 64 + wave * 16;
    const int n0 = blockIdx.x * 64;
    const bf16x8v* Ap = (const bf16x8v*)(A + (m0 + l16) * DD) + quad;
    const bf16x8v* Bp = (const bf16x8v*)(Bm + (n0 + l16) * DD) + quad;
    f32x4v acc0 = {0.f,0.f,0.f,0.f}, acc1 = acc0, acc2 = acc0, acc3 = acc0;
    #pragma unroll 4
    for (int k = 0; k < 16; ++k) {
        const bf16x8v a = Ap[k * 4];
        acc0 = __builtin_amdgcn_mfma_f32_16x16x32_bf16(a, Bp[k * 4       ], acc0, 0, 0, 0);
        acc1 = __builtin_amdgcn_mfma_f32_16x16x32_bf16(a, Bp[k * 4 + 1024], acc1, 0, 0, 0);
        acc2 = __builtin_amdgcn_mfma_f32_16x16x32_bf16(a, Bp[k * 4 + 2048], acc2, 0, 0, 0);
        acc3 = __builtin_amdgcn_mfma_f32_16x16x32_bf16(a, Bp[k * 4 + 3072], acc3, 0, 0, 0);
    }
    const f32x4v accs[4] = {acc0, acc1, acc2, acc3};
    const int gm0 = m0 + quad * 4;
    #pragma unroll
    for (int t = 0; t < 4; ++t) {
        const int gn = n0 + t * 16 + l16;
        const int mat = gn >> 9, d = gn & 511, h = d >> 6, c = d & 63;
        unsigned short* dst = mat ? KV_bf : Q_bf;
        ushort4 pk;
        pk.x = f2bf(accs[t][0]); pk.y = f2bf(accs[t][1]);
        pk.z = f2bf(accs[t][2]); pk.w = f2bf(accs[t][3]);
        dst[(gm0 + 0) * DD + d] = pk.x;
        dst[(gm0 + 1) * DD + d] = pk.y;
        dst[(gm0 + 2) * DD + d] = pk.z;
        dst[(gm0 + 3) * DD + d] = pk.w;
        if (mat) {
            const int b = gm0 >> 7, l0 = gm0 & 127;
            *(ushort4*)&KVT_bf[(((b * HH + h) * CC + c) << 7) + l0] = pk;
        }
    }
}

// ---------------------------------------------------------------------------
// qk_t_gemm: blockIdx.x<256: S1[b,h,q,k] = Q_h @ KV_h^T (fp32).
//            blockIdx.x>=256: T_bf[bq, h*64+x] = Q_h @ We_h^T (bf16).
// ---------------------------------------------------------------------------
__global__ __launch_bounds__(256) void qk_t_gemm(
    const unsigned short* __restrict__ Q_bf, const unsigned short* __restrict__ KV_bf,
    const unsigned short* __restrict__ We_bf,
    float* __restrict__ S1, unsigned short* __restrict__ T_bf)
{
    const int wave = threadIdx.x >> 6, lane = threadIdx.x & 63;
    const int quad = lane >> 4, l16 = lane & 15;
    const int bid = blockIdx.x;
    f32x4v acc[4];
    #pragma unroll
    for (int t = 0; t < 4; ++t) acc[t] = (f32x4v){0.f,0.f,0.f,0.f};

    if (bid < 256) {
        const int batch = bid >> 2, sub = bid & 3;
        const int b = batch >> 3, h = batch & 7;
        const int q0 = (sub >> 1) * 64 + wave * 16;
        const int k0 = (sub & 1) * 64;
        const unsigned short* Ap = Q_bf + (b * LL + q0 + l16) * DD + h * CC + quad * 8;
        #pragma unroll
        for (int ks = 0; ks < 2; ++ks) {
            const bf16x8v a = *(const bf16x8v*)(Ap + ks * 32);
            #pragma unroll
            for (int t = 0; t < 4; ++t) {
                const bf16x8v bb = *(const bf16x8v*)(KV_bf + (b * LL + k0 + t * 16 + l16) * DD + h * CC + quad * 8 + ks * 32);
                acc[t] = __builtin_amdgcn_mfma_f32_16x16x32_bf16(a, bb, acc[t], 0, 0, 0);
            }
        }
        #pragma unroll
        for (int t = 0; t < 4; ++t)
            #pragma unroll
            for (int r = 0; r < 4; ++r)
                S1[((batch * LL + q0 + quad * 4 + r) << 7) + k0 + t * 16 + l16] = acc[t][r];
    } else {
        const int bid2 = bid - 256;
        const int h = bid2 >> 4;
        const int m0 = (bid2 & 15) * 64 + wave * 16;
        const unsigned short* Ap = Q_bf + (m0 + l16) * DD + h * CC + quad * 8;
        #pragma unroll
        for (int ks = 0; ks < 2; ++ks) {
            const bf16x8v a = *(const bf16x8v*)(Ap + ks * 32);
            #pragma unroll
            for (int t = 0; t < 4; ++t) {
                const bf16x8v bb = *(const bf16x8v*)(We_bf + (t * 16 + l16) * DD + h * CC + quad * 8 + ks * 32);
                acc[t] = __builtin_amdgcn_mfma_f32_16x16x32_bf16(a, bb, acc[t], 0, 0, 0);
            }
        }
        #pragma unroll
        for (int t = 0; t < 4; ++t)
            #pragma unroll
            for (int r = 0; r < 4; ++r)
                T_bf[(m0 + quad * 4 + r) * DD + h * CC + t * 16 + l16] = f2bf(acc[t][r]);
    }
}

// ---------------------------------------------------------------------------
// attn_fused: one block per (b,q).
//  - stage e tile to LDS in (k,x) and (x,k) bf16 layouts
//  - S2 = E @ T^T via MFMA (N=8 padded to 16); s = leaky((S1+S2)/8) masked
//  - softmax over k per head (wave-shuffle, norm folded into P)
//  - write P1 (b,h,q,k) bf16; G = P @ E^T via MFMA -> G_bf (bq, h*64+x)
// ---------------------------------------------------------------------------
#define ES 72      // lds_e row stride (ushort):   144B -> bank rot 4
#define ETS 136    // lds_eT/p_bf row stride:      272B -> bank rot 4
__global__ __launch_bounds__(256) void attn_fused(
    const float* __restrict__ e, const int* __restrict__ adj,
    const float* __restrict__ S1, const unsigned short* __restrict__ T_bf,
    unsigned short* __restrict__ P1, unsigned short* __restrict__ G_bf)
{
    __shared__ unsigned short lds_e[LL * ES];     // 18432 B
    __shared__ unsigned short lds_eT[EE * ETS];   // 17408 B
    __shared__ float s_lds[HH * 132];             //  4224 B
    __shared__ unsigned short p_bf[HH * ETS];     //  2176 B

    const int bq = blockIdx.x;
    const int b = bq >> 7, q = bq & 127;
    const int tid = threadIdx.x;
    const int wave = tid >> 6, lane = tid & 63, quad = lane >> 4, l16 = lane & 15;

    // ---- stage e tile (read once, coalesced float4) ----
    const float4* e4 = (const float4*)(e + (size_t)bq * (LL * EE));
    #pragma unroll
    for (int rep = 0; rep < 8; ++rep) {
        const int j = rep * 256 + tid;           // float4 index in tile
        const float4 v = e4[j];
        const int k = j >> 4, x0 = (j & 15) * 4;
        ushort4 u; u.x = f2bf(v.x); u.y = f2bf(v.y); u.z = f2bf(v.z); u.w = f2bf(v.w);
        *(ushort4*)&lds_e[k * ES + x0] = u;
        lds_eT[(x0    ) * ETS + k] = u.x;
        lds_eT[(x0 + 1) * ETS + k] = u.y;
        lds_eT[(x0 + 2) * ETS + k] = u.z;
        lds_eT[(x0 + 3) * ETS + k] = u.w;
    }
    __syncthreads();

    // ---- scores: wave handles k-band [wave*32, wave*32+32) ----
    const int hh = l16 < 8 ? l16 : 7;
    const unsigned short* Trow = T_bf + bq * DD + hh * CC + quad * 8;
    const bf16x8v tb0 = *(const bf16x8v*)(Trow);
    const bf16x8v tb1 = *(const bf16x8v*)(Trow + 32);
    f32x4v sacc[2];
    #pragma unroll
    for (int mt = 0; mt < 2; ++mt) {
        sacc[mt] = (f32x4v){0.f,0.f,0.f,0.f};
        const int kb = wave * 32 + mt * 16;
        const bf16x8v a0 = *(const bf16x8v*)&lds_e[(kb + l16) * ES + quad * 8];
        const bf16x8v a1 = *(const bf16x8v*)&lds_e[(kb + l16) * ES + 32 + quad * 8];
        sacc[mt] = __builtin_amdgcn_mfma_f32_16x16x32_bf16(a0, tb0, sacc[mt], 0, 0, 0);
        sacc[mt] = __builtin_amdgcn_mfma_f32_16x16x32_bf16(a1, tb1, sacc[mt], 0, 0, 0);
    }
    if (l16 < 8) {
        #pragma unroll
        for (int mt = 0; mt < 2; ++mt) {
            const int kk0 = wave * 32 + mt * 16 + quad * 4;
            const float4 s1v = *(const float4*)&S1[(((b * HH + l16) * LL + q) << 7) + kk0];
            const int4 av = *(const int4*)&adj[bq * LL + kk0];
            float sv[4] = {s1v.x, s1v.y, s1v.z, s1v.w};
            const int am[4] = {av.x, av.y, av.z, av.w};
            float4 o;
            float* op = (float*)&o;
            #pragma unroll
            for (int r = 0; r < 4; ++r) {
                float sc = (sv[r] + sacc[mt][r]) * 0.125f;
                sc = (sc >= 0.f) ? sc : SLOPE * sc;
                op[r] = (am[r] == 0) ? -1e9f : sc;
            }
            *(float4*)&s_lds[l16 * 132 + kk0] = o;
        }
    }
    __syncthreads();

    // ---- softmax per head: 32 threads/head, norm folded into P ----
    {
        const int h = tid >> 5, t5 = tid & 31;
        float m = -INFINITY;
        #pragma unroll
        for (int i = 0; i < 4; ++i) m = fmaxf(m, s_lds[h * 132 + t5 + i * 32]);
        #pragma unroll
        for (int off = 16; off > 0; off >>= 1) m = fmaxf(m, __shfl_down(m, off, 32));
        m = __shfl(m, 0, 32);
        const int k0 = t5 * 4;
        float ev[4];
        #pragma unroll
        for (int i = 0; i < 4; ++i) ev[i] = expf(s_lds[h * 132 + k0 + i] - m);
        float l = ev[0] + ev[1] + ev[2] + ev[3];
        #pragma unroll
        for (int off = 16; off > 0; off >>= 1) l += __shfl_down(l, off, 32);
        l = __shfl(l, 0, 32);
        const float inv = 1.f / l;
        ushort4 pk;
        pk.x = f2bf(ev[0] * inv); pk.y = f2bf(ev[1] * inv);
        pk.z = f2bf(ev[2] * inv); pk.w = f2bf(ev[3] * inv);
        *(ushort4*)&p_bf[h * ETS + k0] = pk;
        *(ushort4*)&P1[(((b * HH + h) * LL + q) << 7) + k0] = pk;
    }
    __syncthreads();

    // ---- G = P @ E^T : wave handles x-band [wave*16, wave*16+16) ----
    {
        const int hr = l16 < 8 ? l16 : 0;
        f32x4v g = {0.f,0.f,0.f,0.f};
        #pragma unroll
        for (int ks = 0; ks < 4; ++ks) {
            const bf16x8v a  = *(const bf16x8v*)&p_bf[hr * ETS + ks * 32 + quad * 8];
            const bf16x8v bb = *(const bf16x8v*)&lds_eT[(wave * 16 + l16) * ETS + ks * 32 + quad * 8];
            g = __builtin_amdgcn_mfma_f32_16x16x32_bf16(a, bb, g, 0, 0, 0);
        }
        if (quad < 2) {
            #pragma unroll
            for (int r = 0; r < 4; ++r)
                G_bf[bq * DD + (quad * 4 + r) * CC + wave * 16 + l16] = f2bf(g[r]);
        }
    }
}

// ---------------------------------------------------------------------------
// pv_gemm: O1[bq,d] = P1_h @ KV_h (batched over b,h).  M=128(q) N=64(c) K=128(k)
// ---------------------------------------------------------------------------
__global__ __launch_bounds__(256) void pv_gemm(
    const unsigned short* __restrict__ P1, const unsigned short* __restrict__ KVT_bf,
    float* __restrict__ O1)
{
    const int wave = threadIdx.x >> 6, lane = threadIdx.x & 63;
    const int quad = lane >> 4, l16 = lane & 15;
    const int batch = blockIdx.x >> 1;           // b*8+h
    const int q0 = (blockIdx.x & 1) * 64 + wave * 16;
    const int b = batch >> 3, h = batch & 7;
    f32x4v acc[4];
    #pragma unroll
    for (int t = 0; t < 4; ++t) acc[t] = (f32x4v){0.f,0.f,0.f,0.f};
    const unsigned short* Ap = P1 + ((batch * LL + q0 + l16) << 7) + quad * 8;
    #pragma unroll
    for (int ks = 0; ks < 4; ++ks) {
        const bf16x8v a = *(const bf16x8v*)(Ap + ks * 32);
        #pragma unroll
        for (int t = 0; t < 4; ++t) {
            const bf16x8v bb = *(const bf16x8v*)(KVT_bf + (((batch * CC + t * 16 + l16)) << 7) + quad * 8 + ks * 32);
            acc[t] = __builtin_amdgcn_mfma_f32_16x16x32_bf16(a, bb, acc[t], 0, 0, 0);
        }
    }
    #pragma unroll
    for (int t = 0; t < 4; ++t)
        #pragma unroll
        for (int r = 0; r < 4; ++r)
            O1[(b * LL + q0 + quad * 4 + r) * DD + h * CC + t * 16 + l16] = acc[t][r];
}

// ---------------------------------------------------------------------------
// o2_gemm: attn_bf[bq,d] = bf16( G_h @ We_h + O1 )  (batched over h)
// M=1024(bq) N=64(c) K=64(x)
// ---------------------------------------------------------------------------
__global__ __launch_bounds__(256) void o2_gemm(
    const unsigned short* __restrict__ G_bf, const unsigned short* __restrict__ WeT_bf,
    const float* __restrict__ O1, unsigned short* __restrict__ attn_bf)
{
    const int wave = threadIdx.x >> 6, lane = threadIdx.x & 63;
    const int quad = lane >> 4, l16 = lane & 15;
    const int h = blockIdx.x >> 4;
    const int m0 = (blockIdx.x & 15) * 64 + wave * 16;
    f32x4v acc[4];
    #pragma unroll
    for (int t = 0; t < 4; ++t) acc[t] = (f32x4v){0.f,0.f,0.f,0.f};
    const unsigned short* Ap = G_bf + (m0 + l16) * DD + h * CC + quad * 8;
    #pragma unroll
    for (int ks = 0; ks < 2; ++ks) {
        const bf16x8v a = *(const bf16x8v*)(Ap + ks * 32);
        #pragma unroll
        for (int t = 0; t < 4; ++t) {
            const bf16x8v bb = *(const bf16x8v*)(WeT_bf + (h * CC + t * 16 + l16) * EE + quad * 8 + ks * 32);
            acc[t] = __builtin_amdgcn_mfma_f32_16x16x32_bf16(a, bb, acc[t], 0, 0, 0);
        }
    }
    #pragma unroll
    for (int t = 0; t < 4; ++t) {
        const int d = h * CC + t * 16 + l16;
        #pragma unroll
        for (int r = 0; r < 4; ++r) {
            const int row = m0 + quad * 4 + r;
            attn_bf[row * DD + d] = f2bf(acc[t][r] + O1[row * DD + d]);
        }
    }
}

// ---------------------------------------------------------------------------
// ffn_gemm: vals = attn_bf @ Wf + bf (fp32). M=1024 N=512 K=512
// ---------------------------------------------------------------------------
__global__ __launch_bounds__(256) void ffn_gemm(
    const unsigned short* __restrict__ A, const unsigned short* __restrict__ Bm,
    const float* __restrict__ bfv, float* __restrict__ vals)
{
    const int wave = threadIdx.x >> 6, lane = threadIdx.x & 63;
    const int quad = lane >> 4, l16 = lane & 15;
    const int m0 = blockIdx.y * 64 + wave * 16;
    const int n0 = blockIdx.x * 64;
    const bf16x8v* Ap = (const bf16x8v*)(A + (m0 + l16) * DD) + quad;
    const bf16x8v* Bp = (const bf16x8v*)(Bm + (n0 + l16) * DD) + quad;
    f32x4v acc0 = {0.f,0.f,0.f,0.f}, acc1 = acc0, acc2 = acc0, acc3 = acc0;
    #pragma unroll 4
    for (int k = 0; k < 16; ++k) {
        const bf16x8v a = Ap[k * 4];
        acc0 = __builtin_amdgcn_mfma_f32_16x16x32_bf16(a, Bp[k * 4       ], acc0, 0, 0, 0);
        acc1 = __builtin_amdgcn_mfma_f32_16x16x32_bf16(a, Bp[k * 4 + 1024], acc1, 0, 0, 0);
        acc2 = __builtin_amdgcn_mfma_f32_16x16x32_bf16(a, Bp[k * 4 + 2048], acc2, 0, 0, 0);
        acc3 = __builtin_amdgcn_mfma_f32_16x16x32_bf16(a, Bp[k * 4 + 3072], acc3, 0, 0, 0);
    }
    const f32x4v accs[4] = {acc0, acc1, acc2, acc3};
    #pragma unroll
    for (int t = 0; t < 4; ++t) {
        const int gn = n0 + t * 16 + l16;
        const float bias = bfv[gn];
        #pragma unroll
        for (int r = 0; r < 4; ++r)
            vals[(m0 + quad * 4 + r) * DD + gn] = accs[t][r] + bias;
    }
}

// ---------------------------------------------------------------------------
// LayerNorm + ReLU
// ---------------------------------------------------------------------------
__global__ __launch_bounds__(256) void ln_kernel(
    const float* __restrict__ vals, const float* __restrict__ gamma,
    const float* __restrict__ beta, float* __restrict__ out)
{
    __shared__ float red[8];
    __shared__ float stats[2];
    const int row = blockIdx.x;
    const int tid = threadIdx.x;
    const float v0 = vals[row * DD + tid];
    const float v1 = vals[row * DD + tid + 256];
    float ls = v0 + v1;
    float lss = v0 * v0 + v1 * v1;
    #pragma unroll
    for (int off = 32; off > 0; off >>= 1) {
        ls += __shfl_down(ls, off);
        lss += __shfl_down(lss, off);
    }
    const int wid = tid >> 6;
    if ((tid & 63) == 0) { red[wid * 2] = ls; red[wid * 2 + 1] = lss; }
    __syncthreads();
    if (tid == 0) {
        float ts = 0.f, tss = 0.f;
        for (int w = 0; w < 4; ++w) { ts += red[w * 2]; tss += red[w * 2 + 1]; }
        const float mu = ts / (float)DD;
        const float var = tss / (float)DD - mu * mu;
        stats[0] = mu;
        stats[1] = rsqrtf(var + EPS);
    }
    __syncthreads();
    const float mu = stats[0], rsig = stats[1];
    const float o0 = (v0 - mu) * rsig * gamma[tid] + beta[tid];
    const float o1 = (v1 - mu) * rsig * gamma[tid + 256] + beta[tid + 256];
    out[row * DD + tid] = fmaxf(o0, 0.f);
    out[row * DD + tid + 256] = fmaxf(o1, 0.f);
}

// ---------------------------------------------------------------------------
extern "C" void kernel_launch(void* const* d_in, const int* in_sizes, int n_in,
                              void* d_out, int out_size, void* d_ws, size_t ws_size,
                              hipStream_t stream)
{
    const float* x    = (const float*)d_in[0];
    const int*   adj  = (const int*)  d_in[1];
    const float* e    = (const float*)d_in[2];
    const float* Wq   = (const float*)d_in[3];
    const float* Wkv  = (const float*)d_in[4];
    const float* We   = (const float*)d_in[5];
    const float* Wf   = (const float*)d_in[6];
    const float* bf   = (const float*)d_in[7];
    const float* gam  = (const float*)d_in[8];
    const float* bet  = (const float*)d_in[9];
    float* out = (float*)d_out;

    const int MROW = BB * LL;                    // 1024
    char* w = (char*)d_ws;
    unsigned short* Q_bf   = (unsigned short*)(w);                 // 1 MB
    unsigned short* KV_bf  = (unsigned short*)(w + (1u  << 20));   // 1 MB
    unsigned short* KVT_bf = (unsigned short*)(w + (2u  << 20));   // 1 MB
    float*          S1     = (float*)         (w + (3u  << 20));   // 4 MB
    unsigned short* T_bf   = (unsigned short*)(w + (7u  << 20));   // 1 MB
    unsigned short* P1     = (unsigned short*)(w + (8u  << 20));   // 2 MB
    unsigned short* G_bf   = (unsigned short*)(w + (10u << 20));   // 1 MB
    float*          O1     = (float*)         (w + (11u << 20));   // 2 MB
    float*          vals   = (float*)         (w + (13u << 20));   // 2 MB
    unsigned short* xb     = (unsigned short*)(w + (15u << 20));   // 1 MB
    unsigned short* Wqkv_t = (unsigned short*)(w + (16u << 20));   // 1 MB
    unsigned short* Wf_t   = (unsigned short*)(w + (17u << 20));   // 0.5 MB
    unsigned short* We_bf  = (unsigned short*)(w + (17u << 20) + (512u << 10)); // 64 KB
    unsigned short* WeT_bf = (unsigned short*)(w + (17u << 20) + (576u << 10)); // 64 KB

    pack_all<<<1072, 256, 0, stream>>>(x, Wq, Wkv, Wf, We, xb, Wqkv_t, Wf_t, We_bf, WeT_bf);
    proj_gemm<<<dim3(16, 16), 256, 0, stream>>>(xb, Wqkv_t, Q_bf, KV_bf, KVT_bf);
    qk_t_gemm<<<384, 256, 0, stream>>>(Q_bf, KV_bf, We_bf, S1, T_bf);
    attn_fused<<<MROW, 256, 0, stream>>>(e, adj, S1, T_bf, P1, G_bf);
    pv_gemm<<<128, 256, 0, stream>>>(P1, KVT_bf, O1);
    o2_gemm<<<128, 256, 0, stream>>>(G_bf, WeT_bf, O1, (unsigned short*)Q_bf /*reuse? no*/);
    // NOTE: attn_bf must not alias Q_bf (Q no longer needed after qk_t/attn, but
    // keep it clean: reuse xb (done with after proj).
    // (re-launch with correct destination below is not possible; so use xb.)
    ffn_gemm<<<dim3(8, 16), 256, 0, stream>>>((unsigned short*)Q_bf, Wf_t, bf, vals);
    ln_kernel<<<MROW, 256, 0, stream>>>(vals, gam, bet, out);
}